// Round 8
// baseline (149.659 us; speedup 1.0000x reference)
//
#include <hip/hip_runtime.h>

#define NDAYS 250
#define SCALING 12.0f
#define NB 512       // pi_kernel blocks
#define T1 512       // pi_kernel threads/block
#define T2 1024      // finish_kernel threads
#define CHUNK 4      // row-chunks in finish (NB/CHUNK rows each)

typedef float f4 __attribute__((ext_vector_type(4)));
typedef int   i4 __attribute__((ext_vector_type(4)));

// Loss pieces: Pi[d] = sum over flat k in [0,4N) of w[k%N]*t_flat[k]*sigmoid(12*in_flat[k]),
// grouped by date[k%N], where x/t are the [N,4] col-slice flattened sample-major (k=4i+j).
// Thread handles a group of 4 samples (16 elements k=16g..16g+15). Since N%16==0, all 16
// share one q-segment: m = 16g mod N, paired weights/date are 16 CONTIGUOUS elements at m.
// All loads are aligned dwordx4: inputs/targets bytes [80g,80g+80) = 5 float4 each.
__global__ __launch_bounds__(T1) void pi_kernel(
    const float* __restrict__ inputs, const float* __restrict__ targets,
    const float* __restrict__ weights, const int* __restrict__ date,
    float* __restrict__ part, int n) {
    __shared__ float sPi[NDAYS];
    for (int i = threadIdx.x; i < NDAYS; i += T1) sPi[i] = 0.0f;
    __syncthreads();

    const int ng = n >> 2;                    // sample-groups of 4
    const long stride = (long)gridDim.x * T1;
    for (long g = (long)blockIdx.x * T1 + threadIdx.x; g < ng; g += stride) {
        long m = g << 4;                      // k-base = 16g, reduce mod n (k < 4n)
        if (m >= n) m -= n;
        if (m >= n) m -= n;
        if (m >= n) m -= n;
        const float* ip = inputs + g * 20;
        const float* tp = targets + g * 20;
        f4 in5[5], tg5[5];
        #pragma unroll
        for (int e = 0; e < 5; ++e) {
            in5[e] = *(const f4*)(ip + 4 * e);
            tg5[e] = *(const f4*)(tp + 4 * e);
        }
        f4 w4[4]; i4 d4[4];
        #pragma unroll
        for (int e = 0; e < 4; ++e) {
            w4[e] = *(const f4*)(weights + m + 4 * e);
            d4[e] = *(const i4*)(date + m + 4 * e);
        }
        const float* in_f = (const float*)in5;
        const float* tg_f = (const float*)tg5;
        const float* w_f  = (const float*)w4;
        const int*   d_i  = (const int*)d4;
        #pragma unroll
        for (int r = 0; r < 4; ++r) {
            #pragma unroll
            for (int j = 0; j < 4; ++j) {
                const float xin = in_f[5 * r + j];
                const float e1 = __expf(-SCALING * xin);          // v_exp path
                const float sg = __builtin_amdgcn_rcpf(1.0f + e1);
                const float p = tg_f[5 * r + j] * sg * w_f[4 * r + j];
                atomicAdd(&sPi[d_i[4 * r + j]], p);
            }
        }
    }

    __syncthreads();
    float* row = part + (size_t)blockIdx.x * NDAYS;
    for (int i = threadIdx.x; i < NDAYS; i += T1) row[i] = sPi[i];
}

// One block: reduce part[NB][250] -> Pi[250] -> loss. Coalesced: lane d reads part[r][d].
__global__ __launch_bounds__(T2) void finish_kernel(const float* __restrict__ part,
                                                    float* __restrict__ out) {
    __shared__ float red[CHUNK][256];
    __shared__ float ws_s[4], ws_q[4];
    const int t = threadIdx.x;
    const int d = t & 255;      // day (0..255; 250..255 dummy)
    const int c = t >> 8;       // chunk 0..3
    const int rows = NB / CHUNK;

    float acc = 0.0f;
    if (d < NDAYS) {
        const float* p = part + (size_t)c * rows * NDAYS + d;
        #pragma unroll 8
        for (int r = 0; r < rows; ++r) acc += p[(size_t)r * NDAYS];
    }
    red[c][d] = acc;
    __syncthreads();

    float s = 0.0f, q = 0.0f;
    if (t < 256) {
        const float p4 = red[0][t] + red[1][t] + red[2][t] + red[3][t];
        s = p4;
        q = p4 * p4;
    }
    #pragma unroll
    for (int off = 32; off > 0; off >>= 1) {
        s += __shfl_down(s, off);
        q += __shfl_down(q, off);
    }
    if (t < 256 && (t & 63) == 0) {
        ws_s[t >> 6] = s;
        ws_q[t >> 6] = q;
    }
    __syncthreads();
    if (t == 0) {
        const float sumPi = ws_s[0] + ws_s[1] + ws_s[2] + ws_s[3];
        const float sumPi2 = ws_q[0] + ws_q[1] + ws_q[2] + ws_q[3];
        out[0] = -1.0f * sumPi * fmaxf(sumPi, 0.0f) / sumPi2 / (float)NDAYS;
    }
}

extern "C" void kernel_launch(void* const* d_in, const int* in_sizes, int n_in,
                              void* d_out, int out_size, void* d_ws, size_t ws_size,
                              hipStream_t stream) {
    const float* inputs  = (const float*)d_in[0];
    const float* targets = (const float*)d_in[1];
    const float* weights = (const float*)d_in[2];
    const int*   date    = (const int*)d_in[3];
    float* out  = (float*)d_out;
    float* part = (float*)d_ws;   // NB*NDAYS floats = 512 KB

    const int n = in_sizes[2];    // N (weights is [N])

    pi_kernel<<<NB, T1, 0, stream>>>(inputs, targets, weights, date, part, n);
    finish_kernel<<<1, T2, 0, stream>>>(part, out);
}

// Round 11
// 131.314 us; speedup vs baseline: 1.1397x; 1.1397x over previous
//
#include <hip/hip_runtime.h>

#define NDAYS 250
#define SCALING 12.0f
#define NBLK 512       // pi blocks (4 waves each)
#define TPB 256
#define MIDB 64        // mid blocks; each reduces NBLK/MIDB = 8 rows
#define RPM (NBLK / MIDB)

typedef float f4 __attribute__((ext_vector_type(4)));
typedef int   i4 __attribute__((ext_vector_type(4)));

// Pi[d] = sum over k in [0,4N): w[k%N]*t_flat[k]*sigmoid(12*in_flat[k]) grouped by date[k%N].
// k = q*N + m; i = q*(N/4) + (m>>2); j = m&3; flat = i*5 + j.
// Thread <-> 16-m block s (m = 16s..16s+15, rows 4s..4s+3 per q). Per q: 5+5 aligned f4 row
// loads; accumulate acc[16] across q FIRST, then ONE ds_add per m (4 elements/atomic).
// LDS-atomic lane-ops: 2M total (round-8's 8M was the regression).
__global__ __launch_bounds__(TPB) void pi_kernel(
    const float* __restrict__ inputs, const float* __restrict__ targets,
    const float* __restrict__ weights, const int* __restrict__ date,
    float* __restrict__ part, int n) {
    __shared__ float sPi[NDAYS];
    for (int i = threadIdx.x; i < NDAYS; i += TPB) sPi[i] = 0.0f;
    __syncthreads();

    const int nq = n >> 2;   // rows per q-segment
    const int ns = n >> 4;   // 16-m blocks
    const int s = blockIdx.x * TPB + threadIdx.x;
    if (s < ns) {
        float acc[16];
        #pragma unroll
        for (int mm = 0; mm < 16; ++mm) acc[mm] = 0.0f;

        #pragma unroll
        for (int q = 0; q < 4; ++q) {
            const size_t rowbase = ((size_t)q * nq + 4 * (size_t)s) * 5;
            const float* ip = inputs + rowbase;   // 16B-aligned: q*nq*20B and 80s both 16B-mult
            const float* tp = targets + rowbase;
            f4 in5[5], tg5[5];
            #pragma unroll
            for (int e = 0; e < 5; ++e) {
                in5[e] = *(const f4*)(ip + 4 * e);
                tg5[e] = *(const f4*)(tp + 4 * e);
            }
            const float* in_f = (const float*)in5;
            const float* tg_f = (const float*)tg5;
            #pragma unroll
            for (int r = 0; r < 4; ++r) {
                #pragma unroll
                for (int j = 0; j < 4; ++j) {
                    const float xin = in_f[5 * r + j];
                    const float e1 = __expf(-SCALING * xin);
                    const float sg = __builtin_amdgcn_rcpf(1.0f + e1);
                    acc[4 * r + j] += tg_f[5 * r + j] * sg;
                }
            }
        }

        const long m0 = (long)s << 4;
        f4 w4[4]; i4 d4[4];
        #pragma unroll
        for (int e = 0; e < 4; ++e) {
            w4[e] = *(const f4*)(weights + m0 + 4 * e);
            d4[e] = *(const i4*)(date + m0 + 4 * e);
        }
        const float* w_f = (const float*)w4;
        const int*   d_i = (const int*)d4;
        #pragma unroll
        for (int mm = 0; mm < 16; ++mm)
            atomicAdd(&sPi[d_i[mm]], acc[mm] * w_f[mm]);
    }

    __syncthreads();
    float* row = part + (size_t)blockIdx.x * NDAYS;
    for (int i = threadIdx.x; i < NDAYS; i += TPB) row[i] = sPi[i];
}

// 64 blocks: block b reduces part rows b*8..b*8+7 -> part2[b][250]. Coalesced (lane = col).
__global__ __launch_bounds__(TPB) void mid_kernel(const float* __restrict__ part,
                                                  float* __restrict__ part2) {
    const int c = threadIdx.x;
    if (c < NDAYS) {
        const float* p = part + (size_t)blockIdx.x * RPM * NDAYS + c;
        float a = 0.0f;
        #pragma unroll
        for (int r = 0; r < RPM; ++r) a += p[(size_t)r * NDAYS];
        part2[(size_t)blockIdx.x * NDAYS + c] = a;
    }
}

// 1 block: Pi[c] = sum of MIDB rows of part2; then loss.
__global__ __launch_bounds__(TPB) void fin_kernel(const float* __restrict__ part2,
                                                  float* __restrict__ out) {
    __shared__ float ws_s[4], ws_q[4];
    const int t = threadIdx.x;
    float s = 0.0f, q = 0.0f;
    if (t < NDAYS) {
        float pc = 0.0f;
        #pragma unroll 8
        for (int r = 0; r < MIDB; ++r) pc += part2[(size_t)r * NDAYS + t];
        s = pc;
        q = pc * pc;
    }
    #pragma unroll
    for (int off = 32; off > 0; off >>= 1) {
        s += __shfl_down(s, off);
        q += __shfl_down(q, off);
    }
    if ((t & 63) == 0) {
        ws_s[t >> 6] = s;
        ws_q[t >> 6] = q;
    }
    __syncthreads();
    if (t == 0) {
        const float sumPi  = ws_s[0] + ws_s[1] + ws_s[2] + ws_s[3];
        const float sumPi2 = ws_q[0] + ws_q[1] + ws_q[2] + ws_q[3];
        out[0] = -1.0f * sumPi * fmaxf(sumPi, 0.0f) / sumPi2 / (float)NDAYS;
    }
}

extern "C" void kernel_launch(void* const* d_in, const int* in_sizes, int n_in,
                              void* d_out, int out_size, void* d_ws, size_t ws_size,
                              hipStream_t stream) {
    const float* inputs  = (const float*)d_in[0];
    const float* targets = (const float*)d_in[1];
    const float* weights = (const float*)d_in[2];
    const int*   date    = (const int*)d_in[3];
    float* out   = (float*)d_out;
    float* part  = (float*)d_ws;                       // NBLK*NDAYS floats = 512 KB
    float* part2 = part + (size_t)NBLK * NDAYS;        // MIDB*NDAYS floats = 64 KB

    const int n = in_sizes[2];   // N (weights is [N])

    pi_kernel<<<NBLK, TPB, 0, stream>>>(inputs, targets, weights, date, part, n);
    mid_kernel<<<MIDB, TPB, 0, stream>>>(part, part2);
    fin_kernel<<<1, TPB, 0, stream>>>(part2, out);
}

// Round 12
// 125.138 us; speedup vs baseline: 1.1960x; 1.0494x over previous
//
#include <hip/hip_runtime.h>

#define NDAYS 250
#define SCALING 12.0f
#define TPB 256
#define NBLK 512        // >= ceil(nq/TILE) = 489 supertiles; extras write zero rows
#define TILE 1024       // samples per q per supertile (TILE*5 = 5120 floats = 20*TPB f4 chunks)
#define MIDB 64
#define RPM (NBLK / MIDB)

typedef float f4 __attribute__((ext_vector_type(4)));

// Pi[d] = sum over k in [0,4N): w[k%N]*t_flat[k]*sigmoid(12*in_flat[k]) by date[k%N].
// k = 4i+j (sample-major), i = q*nq+ii -> m = k%N = 4*ii+j.
// COALESCED layout: block owns ii-tile of 1024 samples (all 4 q's). Thread t owns f4
// chunks {256e+t, e<5} of the 5120-float tile -> global loads are lane-stride 16 B.
// Chunk float positions are q-independent: metadata (m, day, weight, validity) computed
// once; acc[5][4] accumulates t*sigmoid across q in registers; one LDS atomic per element.
// Invalid elements (resp col j==4, or tail beyond tile): weight=0, day=lane (adds 0.0,
// lane-distinct so no same-address atomic serialization).
__global__ __launch_bounds__(TPB) void pi_kernel(
    const float* __restrict__ inputs, const float* __restrict__ targets,
    const float* __restrict__ weights, const int* __restrict__ date,
    float* __restrict__ part, int n) {
    __shared__ float sPi[NDAYS];
    for (int i = threadIdx.x; i < NDAYS; i += TPB) sPi[i] = 0.0f;
    __syncthreads();

    const int nq = n >> 2;                 // samples per q-segment
    const int ii0 = blockIdx.x * TILE;
    if (ii0 < nq) {
        const int ts  = min(TILE, nq - ii0);   // samples in this tile
        const int nfl = ts * 5;                // valid floats per array per q
        const int lane = threadIdx.x & 63;

        int   dy[5][4];
        float wt[5][4];
        #pragma unroll
        for (int e = 0; e < 5; ++e) {
            const int c   = TPB * e + threadIdx.x;  // chunk id in tile
            const int fl0 = 4 * c;
            #pragma unroll
            for (int dlt = 0; dlt < 4; ++dlt) {
                const int fl = fl0 + dlt;
                const int si = (int)(((unsigned)fl * 52429u) >> 18);  // fl/5 (exact, fl<5120)
                const int j  = fl - 5 * si;
                const bool valid = (fl < nfl) && (j < 4);
                const int  m = valid ? (4 * (ii0 + si) + j) : 0;
                wt[e][dlt] = valid ? weights[m] : 0.0f;
                dy[e][dlt] = valid ? date[m] : lane;
            }
        }

        float acc[5][4] = {};
        #pragma unroll
        for (int q = 0; q < 4; ++q) {
            const size_t base = ((size_t)q * nq + ii0) * 5;   // 16B-aligned
            #pragma unroll
            for (int e = 0; e < 5; ++e) {
                const int c = TPB * e + threadIdx.x;
                f4 inv = {0.0f, 0.0f, 0.0f, 0.0f};
                f4 tgv = {0.0f, 0.0f, 0.0f, 0.0f};
                if (4 * c < nfl) {
                    inv = *(const f4*)(inputs + base + 4 * c);
                    tgv = *(const f4*)(targets + base + 4 * c);
                }
                #pragma unroll
                for (int dlt = 0; dlt < 4; ++dlt) {
                    const float e1 = __expf(-SCALING * inv[dlt]);
                    const float sg = __builtin_amdgcn_rcpf(1.0f + e1);
                    acc[e][dlt] += tgv[dlt] * sg;
                }
            }
        }

        #pragma unroll
        for (int e = 0; e < 5; ++e)
            #pragma unroll
            for (int dlt = 0; dlt < 4; ++dlt)
                atomicAdd(&sPi[dy[e][dlt]], acc[e][dlt] * wt[e][dlt]);
    }

    __syncthreads();
    float* row = part + (size_t)blockIdx.x * NDAYS;
    for (int i = threadIdx.x; i < NDAYS; i += TPB) row[i] = sPi[i];
}

// 64 blocks: block b reduces part rows b*8..b*8+7 -> part2[b][250]. Coalesced (lane = col).
__global__ __launch_bounds__(TPB) void mid_kernel(const float* __restrict__ part,
                                                  float* __restrict__ part2) {
    const int c = threadIdx.x;
    if (c < NDAYS) {
        const float* p = part + (size_t)blockIdx.x * RPM * NDAYS + c;
        float a = 0.0f;
        #pragma unroll
        for (int r = 0; r < RPM; ++r) a += p[(size_t)r * NDAYS];
        part2[(size_t)blockIdx.x * NDAYS + c] = a;
    }
}

// 1 block: Pi[c] = sum of MIDB rows of part2; then loss.
__global__ __launch_bounds__(TPB) void fin_kernel(const float* __restrict__ part2,
                                                  float* __restrict__ out) {
    __shared__ float ws_s[4], ws_q[4];
    const int t = threadIdx.x;
    float s = 0.0f, q = 0.0f;
    if (t < NDAYS) {
        float pc = 0.0f;
        #pragma unroll 8
        for (int r = 0; r < MIDB; ++r) pc += part2[(size_t)r * NDAYS + t];
        s = pc;
        q = pc * pc;
    }
    #pragma unroll
    for (int off = 32; off > 0; off >>= 1) {
        s += __shfl_down(s, off);
        q += __shfl_down(q, off);
    }
    if ((t & 63) == 0) {
        ws_s[t >> 6] = s;
        ws_q[t >> 6] = q;
    }
    __syncthreads();
    if (t == 0) {
        const float sumPi  = ws_s[0] + ws_s[1] + ws_s[2] + ws_s[3];
        const float sumPi2 = ws_q[0] + ws_q[1] + ws_q[2] + ws_q[3];
        out[0] = -1.0f * sumPi * fmaxf(sumPi, 0.0f) / sumPi2 / (float)NDAYS;
    }
}

extern "C" void kernel_launch(void* const* d_in, const int* in_sizes, int n_in,
                              void* d_out, int out_size, void* d_ws, size_t ws_size,
                              hipStream_t stream) {
    const float* inputs  = (const float*)d_in[0];
    const float* targets = (const float*)d_in[1];
    const float* weights = (const float*)d_in[2];
    const int*   date    = (const int*)d_in[3];
    float* out   = (float*)d_out;
    float* part  = (float*)d_ws;                       // NBLK*NDAYS floats = 512 KB
    float* part2 = part + (size_t)NBLK * NDAYS;        // MIDB*NDAYS floats = 64 KB

    const int n = in_sizes[2];   // N (weights is [N])

    pi_kernel<<<NBLK, TPB, 0, stream>>>(inputs, targets, weights, date, part, n);
    mid_kernel<<<MIDB, TPB, 0, stream>>>(part, part2);
    fin_kernel<<<1, TPB, 0, stream>>>(part2, out);
}